// Round 2
// baseline (1755.528 us; speedup 1.0000x reference)
//
#include <hip/hip_runtime.h>

#define NBATCH 16
#define NPTS   1024
#define NDIM   1024
#define EPSI   1e-3f
#define QSCALE 127.5f

typedef __attribute__((ext_vector_type(8))) short short8;
typedef __attribute__((ext_vector_type(4))) float f32x4;

__device__ __forceinline__ unsigned short f2bf(float f) {
  union { float f; unsigned u; } v; v.f = f;
  unsigned r = v.u + 0x7fffu + ((v.u >> 16) & 1u);
  return (unsigned short)(r >> 16);
}

// device-coherent scalar access (per-access sc bits; NO cache-wide fences)
__device__ __forceinline__ float ld_agent(const float* p) {
  return __hip_atomic_load(p, __ATOMIC_RELAXED, __HIP_MEMORY_SCOPE_AGENT);
}
__device__ __forceinline__ void st_agent(float* p, float v) {
  __hip_atomic_store(p, v, __ATOMIC_RELAXED, __HIP_MEMORY_SCOPE_AGENT);
}
__device__ __forceinline__ unsigned long long ld_agent64(const unsigned long long* p) {
  return __hip_atomic_load(p, __ATOMIC_RELAXED, __HIP_MEMORY_SCOPE_AGENT);
}

// ---------------- normalize: fp32 [B,N,D] -> unit rows, bf16 ----------------
__global__ __launch_bounds__(256) void norm_kernel(const float* __restrict__ x,
                                                   const float* __restrict__ y,
                                                   unsigned short* __restrict__ xf,
                                                   unsigned short* __restrict__ yf) {
  int row = blockIdx.x;
  const float* src; unsigned short* dst;
  if (row < NBATCH * NPTS) { src = x; dst = xf; }
  else { row -= NBATCH * NPTS; src = y; dst = yf; }
  src += (size_t)row * NDIM; dst += (size_t)row * NDIM;
  const int t = threadIdx.x;
  float4 val = ((const float4*)src)[t];
  float ss = val.x*val.x + val.y*val.y + val.z*val.z + val.w*val.w;
  #pragma unroll
  for (int o = 32; o; o >>= 1) ss += __shfl_xor(ss, o, 64);
  __shared__ float wsum[4];
  if ((t & 63) == 0) wsum[t >> 6] = ss;
  __syncthreads();
  float tot = wsum[0] + wsum[1] + wsum[2] + wsum[3];
  float inv = 1.0f / fmaxf(sqrtf(tot), 1e-12f);
  ushort4 o4;
  o4.x = f2bf(val.x * inv); o4.y = f2bf(val.y * inv);
  o4.z = f2bf(val.z * inv); o4.w = f2bf(val.w * inv);
  ((ushort4*)dst)[t] = o4;
}

// ------- batched bf16 GEMM: writes BOTH Cq = q8(1 - A B^T) and its transpose -------
#define GLD_LDS16(g, l) __builtin_amdgcn_global_load_lds( \
    (const __attribute__((address_space(1))) unsigned int*)(g), \
    (__attribute__((address_space(3))) unsigned int*)(l), 16, 0, 0)

__device__ __forceinline__ unsigned char q8(float cv) {
  float t = cv * QSCALE + 0.5f;
  t = fminf(fmaxf(t, 0.f), 255.f);
  return (unsigned char)(int)t;
}

__global__ __launch_bounds__(256) void gemm_cost(const unsigned short* __restrict__ A,
                                                 const unsigned short* __restrict__ B,
                                                 unsigned char* __restrict__ Cq,
                                                 unsigned char* __restrict__ CTq,
                                                 unsigned* __restrict__ cmax_bits) {
  const int b = blockIdx.z;
  const int bm = blockIdx.y * 128, bn = blockIdx.x * 128;
  const int t = threadIdx.x, lane = t & 63, wv = t >> 6;
  const int wm = (wv & 1) * 64, wn = (wv >> 1) * 64;
  __shared__ unsigned short As[128 * 32];
  __shared__ unsigned short Bs[128 * 32];
  f32x4 acc[4][4];
  #pragma unroll
  for (int i = 0; i < 4; ++i)
    #pragma unroll
    for (int j = 0; j < 4; ++j) acc[i][j] = (f32x4){0.f, 0.f, 0.f, 0.f};

  const unsigned short* gA = A + (size_t)b*NPTS*NDIM + (size_t)(bm + (t >> 2))*NDIM + (t & 3)*8;
  const unsigned short* gB = B + (size_t)b*NPTS*NDIM + (size_t)(bn + (t >> 2))*NDIM + (t & 3)*8;
  const int ar = lane & 15, ak = (lane >> 4) * 8;

  for (int k0 = 0; k0 < NDIM; k0 += 32) {
    GLD_LDS16(gA + k0,             As + t*8);
    GLD_LDS16(gA + 64*NDIM + k0,   As + 2048 + t*8);
    GLD_LDS16(gB + k0,             Bs + t*8);
    GLD_LDS16(gB + 64*NDIM + k0,   Bs + 2048 + t*8);
    __syncthreads();
    short8 af[4], bq[4];
    #pragma unroll
    for (int i = 0; i < 4; ++i) af[i] = *(const short8*)(As + (wm + i*16 + ar)*32 + ak);
    #pragma unroll
    for (int j = 0; j < 4; ++j) bq[j] = *(const short8*)(Bs + (wn + j*16 + ar)*32 + ak);
    #pragma unroll
    for (int i = 0; i < 4; ++i)
      #pragma unroll
      for (int j = 0; j < 4; ++j)
        acc[i][j] = __builtin_amdgcn_mfma_f32_16x16x32_bf16(af[i], bq[j], acc[i][j], 0, 0, 0);
    __syncthreads();
  }

  float mx = 0.f;
  const int cr = (lane >> 4) * 4, cc = lane & 15;
  unsigned char* Cb = Cq  + (size_t)b * NPTS * NPTS;
  unsigned char* Tb = CTq + (size_t)b * NPTS * NPTS;
  #pragma unroll
  for (int i = 0; i < 4; ++i) {
    #pragma unroll
    for (int j = 0; j < 4; ++j) {
      const int row0 = bm + wm + i*16 + cr;
      const int col  = bn + wn + j*16 + cc;
      #pragma unroll
      for (int r = 0; r < 4; ++r) {
        float cv = 1.0f - acc[i][j][r];
        mx = fmaxf(mx, cv);
        unsigned char qv = q8(cv);
        Cb[(size_t)(row0 + r) * NPTS + col] = qv;
        Tb[(size_t)col * NPTS + row0 + r]   = qv;
      }
    }
  }
  #pragma unroll
  for (int o = 32; o; o >>= 1) mx = fmaxf(mx, __shfl_xor(mx, o, 64));
  if (lane == 0) atomicMax(cmax_bits, __float_as_uint(mx));
}

// ---------------- persistent Sinkhorn: barrier-free, matrix-in-VGPR ----------------
// 256 WGs x 512 thr. WG = (b, s) owns 64 COMPLETE outputs [s*64, s*64+64) of both
// u and v (full 1024-wide reduction; no cross-WG partials). Matrix slices for C
// and CT are loaded into VGPRs ONCE (they never change): wave w, pass p handles
// row ob+p*8+w; lane l holds bytes [16l,16l+16) of that row (uint4), coalesced.
//
// Synchronization = per-value sign-parity tags. All stored u/v values are
// strictly positive; write #k is stored negated per a fixed parity schedule
// (v#k negative iff k odd; u#k negative iff k even). Zeroed workspace matches
// no tag. Causality: producing write #k+1 requires this WG consumed all of
// write #k, which requires every WG produced write #k, which required each to
// consume write #k-1 -- so a polled slot only ever holds tag #k-1 (spin) or
// #k (proceed); same-sign #k-2 / #k+2 are unreachable. 256 WGs, >=1 WG/CU
// (launch_bounds caps VGPR<=256) -> all co-resident.

__device__ __forceinline__ float dot16(uint4 q, f32x4 g0, f32x4 g1, f32x4 g2, f32x4 g3) {
  float a = 0.f;
  a += (float)( q.x        & 0xffu) * g0.x;   // v_cvt_f32_ubyte0
  a += (float)((q.x >>  8) & 0xffu) * g0.y;
  a += (float)((q.x >> 16) & 0xffu) * g0.z;
  a += (float)( q.x >> 24         ) * g0.w;
  a += (float)( q.y        & 0xffu) * g1.x;
  a += (float)((q.y >>  8) & 0xffu) * g1.y;
  a += (float)((q.y >> 16) & 0xffu) * g1.z;
  a += (float)( q.y >> 24         ) * g1.w;
  a += (float)( q.z        & 0xffu) * g2.x;
  a += (float)((q.z >>  8) & 0xffu) * g2.y;
  a += (float)((q.z >> 16) & 0xffu) * g2.z;
  a += (float)( q.z >> 24         ) * g2.w;
  a += (float)( q.w        & 0xffu) * g3.x;
  a += (float)((q.w >>  8) & 0xffu) * g3.y;
  a += (float)((q.w >> 16) & 0xffu) * g3.z;
  a += (float)( q.w >> 24         ) * g3.w;
  return a;
}

// poll this thread's 2 adjacent values as ONE 64-bit relaxed agent load until
// both sign-tags match (positive tag additionally requires nonzero magnitude,
// so a zeroed workspace never matches). Tight spin ~32 tries, then s_sleep
// backoff so 128K spinning threads don't starve producers on the fabric.
// Stage |v| into LDS at bit-permuted position: value m lives at float-index
// ((m>>2)&3)*256 + (m>>4)*4 + (m&3)  => lane l later reads its 16 g's as 4
// conflict-free ds_read_b128 (contiguous 16B per lane).
__device__ __forceinline__ void poll_stage(const float* __restrict__ src, float* dst,
                                           int tid, int i0, bool expneg) {
  const unsigned long long* p0 = (const unsigned long long*)(src + 2 * tid);
  const unsigned long long SGN = 0x8000000080000000ull;
  unsigned long long t = ld_agent64(p0);
  int spins = 0;
  if (expneg) {
    while ((t & SGN) != SGN) {
      if (++spins > 32) __builtin_amdgcn_s_sleep(1);
      t = ld_agent64(p0);
    }
  } else {
    while ((t & SGN) != 0ull ||
           (t & 0x7fffffffull) == 0ull ||
           (t & 0x7fffffff00000000ull) == 0ull) {
      if (++spins > 32) __builtin_amdgcn_s_sleep(1);
      t = ld_agent64(p0);
    }
  }
  union { unsigned u; float f; } lo, hi;
  lo.u = (unsigned)t & 0x7fffffffu;
  hi.u = (unsigned)(t >> 32) & 0x7fffffffu;
  dst[i0]     = lo.f;
  dst[i0 + 1] = hi.f;
}

#define LOAD_G(buf)                                          \
  const f32x4 g0 = *(const f32x4*)&buf[      lane * 4];      \
  const f32x4 g1 = *(const f32x4*)&buf[256 + lane * 4];      \
  const f32x4 g2 = *(const f32x4*)&buf[512 + lane * 4];      \
  const f32x4 g3 = *(const f32x4*)&buf[768 + lane * 4];

__global__ __launch_bounds__(512) void sinkhorn_kernel(
    const unsigned char* __restrict__ Cq, const unsigned char* __restrict__ CTq,
    float* __restrict__ ubuf, float* __restrict__ vbuf,
    float* __restrict__ dist, const unsigned* __restrict__ cmax_bits)
{
  const int wg = blockIdx.x;
  const int b = wg & (NBATCH - 1);
  const int s = wg >> 4;
  const int ob = s * 64;
  const int tid = threadIdx.x, lane = tid & 63, w = tid >> 6;

  __shared__ __align__(16) float gb0[1024];   // U-phase staging (and distance)
  __shared__ __align__(16) float gb1[1024];   // V-phase staging

  const float cmax  = __uint_as_float(*cmax_bits);
  const float invc2 = 1.0f / (QSCALE * cmax);   // dequant + /cmax folded

  // one-time matrix load into VGPRs: 8 rows of C + 8 rows of CT per wave
  uint4 mc[8], mt[8];
  {
    const unsigned char* cb = Cq  + (size_t)b * NPTS * NPTS;
    const unsigned char* tb = CTq + (size_t)b * NPTS * NPTS;
    #pragma unroll
    for (int p = 0; p < 8; ++p) {
      const size_t off = (size_t)(ob + p * 8 + w) * NPTS + lane * 16;
      mc[p] = *(const uint4*)(cb + off);
      mt[p] = *(const uint4*)(tb + off);
    }
  }

  float* ub = ubuf + b * NPTS;
  float* vb = vbuf + b * NPTS;

  // v write #0: +1/N (positive tag; zeroed workspace never matches any tag)
  if (tid < 64) st_agent(&vb[ob + tid], 1.0f / (float)NPTS);

  // bit-permuted LDS slot for this thread's 2 staged values (m = 2*tid, 2*tid+1)
  const int i0 = ((tid >> 1) & 3) * 256 + (tid >> 3) * 4 + (tid & 1) * 2;
  float uk[8];   // final g(u) for our 8 rows (for the distance epilogue)

  #pragma unroll 1
  for (int it = 0; it < 100; ++it) {
    const float sgn = (it & 1) ? 1.f : -1.f;   // tag sign for u#it and v#(it+1)

    // ---- U: consume v#it (neg iff it odd), produce u#it (neg iff it even)
    poll_stage(vb, gb0, tid, i0, (it & 1) != 0);
    __syncthreads();
    {
      LOAD_G(gb0);
      #pragma unroll
      for (int p = 0; p < 8; ++p) {
        float acc = dot16(mc[p], g0, g1, g2, g3);
        #pragma unroll
        for (int o = 32; o; o >>= 1) acc += __shfl_xor(acc, o, 64);
        const float val = 1.0f / (acc * invc2 + EPSI);
        uk[p] = val;
        if (lane == 0) st_agent(&ub[ob + p * 8 + w], val * sgn);
      }
    }

    // ---- V: consume u#it (neg iff it even), produce v#(it+1) (neg iff it even)
    poll_stage(ub, gb1, tid, i0, (it & 1) == 0);
    __syncthreads();
    {
      LOAD_G(gb1);
      #pragma unroll
      for (int p = 0; p < 8; ++p) {
        float acc = dot16(mt[p], g0, g1, g2, g3);
        #pragma unroll
        for (int o = 32; o; o >>= 1) acc += __shfl_xor(acc, o, 64);
        const float val = 1.0f / (acc * invc2 + EPSI);
        if (lane == 0) st_agent(&vb[ob + p * 8 + w], val * sgn);
      }
    }
  }

  // ---- distance: d_b = sum_n u_n * (C v)_n ; v write #100 is positive-tagged
  poll_stage(vb, gb0, tid, i0, false);
  __syncthreads();
  {
    LOAD_G(gb0);
    float term = 0.f;
    #pragma unroll
    for (int p = 0; p < 8; ++p) {
      float acc = dot16(mc[p], g0, g1, g2, g3);
      #pragma unroll
      for (int o = 32; o; o >>= 1) acc += __shfl_xor(acc, o, 64);
      term += uk[p] * acc;     // butterfly leaves the sum in every lane
    }
    if (lane == 0) atomicAdd(dist + b, term * invc2);
  }
}

__global__ void finalize_kernel(const float* __restrict__ dist, float* __restrict__ out) {
  if (threadIdx.x == 0) {
    float s = 0.f;
    for (int i = 0; i < NBATCH; ++i) s += dist[i];
    out[0] = s * (1.0f / NBATCH);
  }
}

// ---------------- launch ----------------
extern "C" void kernel_launch(void* const* d_in, const int* in_sizes, int n_in,
                              void* d_out, int out_size, void* d_ws, size_t ws_size,
                              hipStream_t stream) {
  (void)in_sizes; (void)n_in; (void)out_size; (void)ws_size;
  const float* x = (const float*)d_in[0];
  const float* y = (const float*)d_in[1];
  float* out = (float*)d_out;
  char* ws = (char*)d_ws;

  unsigned* cmax_bits = (unsigned*)ws;                 // @0
  float*    dist      = (float*)(ws + 8192);           // 16 floats
  float*    vbuf      = (float*)(ws + 65536);          // 16 x 1024 f32 = 64 KB
  float*    ubuf      = (float*)(ws + 131072);         // 64 KB
  const size_t MB = 1u << 20;
  unsigned short* xf = (unsigned short*)(ws + 1*MB);   // 32 MB bf16
  unsigned short* yf = (unsigned short*)(ws + 33*MB);  // 32 MB bf16
  unsigned char*  C  = (unsigned char*)(ws + 65*MB);   // 16 MB u8
  unsigned char*  CT = (unsigned char*)(ws + 81*MB);   // 16 MB u8

  hipMemsetAsync(d_ws, 0, 262144, stream);  // cmax / dist / u / v (tag protocol needs zeros)

  hipLaunchKernelGGL(norm_kernel, dim3(2 * NBATCH * NPTS), dim3(256), 0, stream, x, y, xf, yf);
  hipLaunchKernelGGL(gemm_cost, dim3(8, 8, NBATCH), dim3(256), 0, stream, xf, yf, C, CT, cmax_bits);
  hipLaunchKernelGGL(sinkhorn_kernel, dim3(256), dim3(512), 0, stream, C, CT, ubuf, vbuf, dist, cmax_bits);
  hipLaunchKernelGGL(finalize_kernel, dim3(1), dim3(64), 0, stream, dist, out);
}